// Round 6
// baseline (336.263 us; speedup 1.0000x reference)
//
#include <hip/hip_runtime.h>

#define EPSF 1e-8f

constexpr int D0 = 128;   // input dim
constexpr int R  = 256;   // random features
constexpr int D1 = 64;    // output dim
constexpr int BM = 32;    // rows per block
constexpr int NT = 256;   // threads per block (4 waves)

typedef __attribute__((ext_vector_type(8))) short  bf16x8;
typedef __attribute__((ext_vector_type(4))) float  f32x4;
typedef __attribute__((ext_vector_type(4))) uint   u32x4;

// ws layout:
//   bytes [0, 229376):  bf16 weight frags (ushort offsets below)
//   then ints: counts[U+1] | cursor[U] | offsets[U+1]
//   then (512-aligned): vals[N][128] f32  — counting-sorted (p, p*m) rows
constexpr int WS_W1VAR = 32768;
constexpr int WS_W2MU  = 65536;
constexpr int WS_W2C   = 81920;
constexpr int WS_W2VAR = 98304;
constexpr size_t WS_WEIGHT_BYTES = 229376;   // 112K ushorts, 512-aligned

__device__ __forceinline__ ushort f2bf(float x) {
    uint32_t u = __builtin_bit_cast(uint32_t, x);
    u += 0x7FFFu + ((u >> 16) & 1u);          // round-to-nearest-even
    return (ushort)(u >> 16);
}

// packed f32x2 -> bf16x2 (RNE), 1 VALU inst
__device__ __forceinline__ uint cvt_pk_bf16(float lo, float hi) {
    uint r;
    asm("v_cvt_pk_bf16_f32 %0, %1, %2" : "=v"(r) : "v"(lo), "v"(hi));
    return r;
}

// elementwise square of a bf16x8 fragment
__device__ __forceinline__ bf16x8 sq_bf16x8(bf16x8 a) {
    u32x4 u = __builtin_bit_cast(u32x4, a);
    u32x4 r;
    #pragma unroll
    for (int i = 0; i < 4; ++i) {
        float lo = __builtin_bit_cast(float, u[i] << 16);
        float hi = __builtin_bit_cast(float, u[i] & 0xFFFF0000u);
        r[i] = cvt_pk_bf16(lo * lo, hi * hi);
    }
    return __builtin_bit_cast(bf16x8, r);
}

// --- pre-kernel: convert weights to bf16 in MFMA fragment order ------------
__global__ void convert_w(const float* __restrict__ W1mu,
                          const float* __restrict__ W1var,
                          const float* __restrict__ W2mu,
                          const float* __restrict__ W2var,
                          ushort* __restrict__ ws)
{
    int tid = blockIdx.x * 256 + threadIdx.x;
    if (tid < 8192) {                       // layer 1: 2 mats * 64 frags * 64 lanes
        int m    = tid >> 12;               // 0=mu 1=var
        int f    = (tid >> 6) & 63;         // frag = nt*4 + ks
        int lane = tid & 63;
        int nt = f >> 2, ks = f & 3;
        int col = nt * 16 + (lane & 15);    // rf index (W1 row)
        int k0  = ks * 32 + (lane >> 4) * 8;
        const float* src = (m ? W1var : W1mu) + (size_t)col * D0 + k0;
        ushort* dst = ws + (m ? WS_W1VAR : 0) + (size_t)(f * 64 + lane) * 8;
        #pragma unroll
        for (int j = 0; j < 8; ++j) dst[j] = f2bf(src[j]);
    } else if (tid < 8192 + 3 * 2048) {     // layer 2: 3 mats * 32 frags * 64 lanes
        int t2   = tid - 8192;
        int m    = t2 >> 11;                // 0=mu 1=c 2=var
        int f    = (t2 >> 6) & 31;          // frag = nt*8 + ks
        int lane = t2 & 63;
        int nt = f >> 3, ks = f & 7;
        int col = nt * 16 + (lane & 15);    // d1 index (W2 row)
        int k0  = ks * 32 + (lane >> 4) * 8;
        const float* smu = W2mu  + (size_t)col * R + k0;
        const float* svr = W2var + (size_t)col * R + k0;
        ushort* dst = ws + WS_W2MU + m * 16384 + (size_t)(f * 64 + lane) * 8;
        #pragma unroll
        for (int j = 0; j < 8; ++j) {
            float v;
            if (m == 0)      v = smu[j];
            else if (m == 1) v = fmaf(smu[j], smu[j], svr[j]);  // var + mu^2
            else             v = svr[j];
            dst[j] = f2bf(v);
        }
    }
}

// --- histogram of segment ids ----------------------------------------------
__global__ void hist_kernel(const int* __restrict__ idx,
                            int* __restrict__ counts, int N)
{
    int i = blockIdx.x * 256 + threadIdx.x;
    if (i < N) atomicAdd(&counts[idx[i]], 1);
}

// --- exclusive prefix sum: counts[0..U) -> offsets[0..U] (disjoint arrays) --
__global__ __launch_bounds__(1024)
void scan_kernel(const int* __restrict__ counts,
                 int* __restrict__ offsets, int U)
{
    __shared__ int ssum[1024];
    const int t = threadIdx.x;
    const int chunk = (U + 1023) / 1024;
    const int base = t * chunk;
    int s = 0;
    for (int i = 0; i < chunk; ++i) {
        int idx = base + i;
        if (idx < U) s += counts[idx];
    }
    ssum[t] = s;
    __syncthreads();
    for (int d = 1; d < 1024; d <<= 1) {
        int v = (t >= d) ? ssum[t - d] : 0;
        __syncthreads();
        ssum[t] += v;
        __syncthreads();
    }
    int run = (t == 0) ? 0 : ssum[t - 1];
    for (int i = 0; i < chunk; ++i) {
        int idx = base + i;
        if (idx <= U) offsets[idx] = run;
        if (idx < U) run += counts[idx];
    }
}

// --- fused main kernel ------------------------------------------------------
template <bool SORTED>
__global__ __launch_bounds__(NT, 4)
void dgp_mfma(const float* __restrict__ X,
              const int*   __restrict__ Xidx,
              const ushort* __restrict__ ws,
              const int*   __restrict__ offsets,
              int*         __restrict__ cursor,
              float*       __restrict__ vals,
              float* __restrict__ accM,
              float* __restrict__ accP)
{
    __shared__ __align__(16) ushort sh[2 * BM * R];
    ushort* M1s = sh;
    ushort* V1s = sh + BM * R;

    const int t    = threadIdx.x;
    const int lane = t & 63;
    const int w    = t >> 6;         // wave 0..3
    const int row0 = blockIdx.x * BM;
    const int lcol = lane & 15;      // X-row within 16-tile
    const int lk   = lane >> 4;      // 0..3

    // ---------------- Layer 1: W1·X^T (mu) and W1var·(X^2)^T ----------------
    f32x4 accm[2][4], accv[2][4];   // [rt][nt]
    #pragma unroll
    for (int rt = 0; rt < 2; ++rt)
        #pragma unroll
        for (int nt = 0; nt < 4; ++nt) {
            accm[rt][nt] = (f32x4)0.f;
            accv[rt][nt] = (f32x4)0.f;
        }

    #pragma unroll
    for (int ks = 0; ks < 4; ++ks) {
        bf16x8 xb[2], xq[2];
        #pragma unroll
        for (int rt = 0; rt < 2; ++rt) {
            const float* xp = X + (size_t)(row0 + rt * 16 + lcol) * D0 + ks * 32 + lk * 8;
            float4 a = *(const float4*)xp;
            float4 b = *(const float4*)(xp + 4);
            u32x4 um, uq;
            um[0] = cvt_pk_bf16(a.x, a.y);
            um[1] = cvt_pk_bf16(a.z, a.w);
            um[2] = cvt_pk_bf16(b.x, b.y);
            um[3] = cvt_pk_bf16(b.z, b.w);
            uq[0] = cvt_pk_bf16(a.x * a.x, a.y * a.y);
            uq[1] = cvt_pk_bf16(a.z * a.z, a.w * a.w);
            uq[2] = cvt_pk_bf16(b.x * b.x, b.y * b.y);
            uq[3] = cvt_pk_bf16(b.z * b.z, b.w * b.w);
            xb[rt] = __builtin_bit_cast(bf16x8, um);
            xq[rt] = __builtin_bit_cast(bf16x8, uq);
        }
        #pragma unroll
        for (int nt = 0; nt < 4; ++nt) {
            int f = (w * 4 + nt) * 4 + ks;
            bf16x8 amu = *(const bf16x8*)(ws + (size_t)(f * 64 + lane) * 8);
            bf16x8 avr = *(const bf16x8*)(ws + WS_W1VAR + (size_t)(f * 64 + lane) * 8);
            #pragma unroll
            for (int rt = 0; rt < 2; ++rt) {
                accm[rt][nt] = __builtin_amdgcn_mfma_f32_16x16x32_bf16(amu, xb[rt], accm[rt][nt], 0, 0, 0);
                accv[rt][nt] = __builtin_amdgcn_mfma_f32_16x16x32_bf16(avr, xq[rt], accv[rt][nt], 0, 0, 0);
            }
        }
    }

    // RF-ReLU epilogue -> b64 LDS writes (XOR-swizzled)
    const float SCALE  = 0.08838834764831845f;  // sqrt(2/256)
    const float SCALE2 = 0.0078125f;            // 2/256
    #pragma unroll
    for (int rt = 0; rt < 2; ++rt) {
        int xrow = rt * 16 + lcol;
        int swz  = (xrow & 7) << 3;
        int rowb = xrow * 256;
        #pragma unroll
        for (int nt = 0; nt < 4; ++nt) {
            int rf0 = (w * 4 + nt) * 16 + lk * 4;
            float m1[4], v1[4];
            #pragma unroll
            for (int i = 0; i < 4; ++i) {
                float om = accm[rt][nt][i];
                float ov = accv[rt][nt][i];
                bool pos = om > 0.f;
                m1[i] = pos ? SCALE  * om : 0.f;
                v1[i] = pos ? SCALE2 * ov : 0.f;
            }
            uint2 pm, pv;
            pm.x = cvt_pk_bf16(m1[0], m1[1]); pm.y = cvt_pk_bf16(m1[2], m1[3]);
            pv.x = cvt_pk_bf16(v1[0], v1[1]); pv.y = cvt_pk_bf16(v1[2], v1[3]);
            int idx = rowb + (rf0 ^ swz);
            *(uint2*)&M1s[idx] = pm;
            *(uint2*)&V1s[idx] = pv;
        }
    }

    __syncthreads();

    // ---------------- Layer 2: W2·slab^T moment GEMMs (K=256) ---------------
    f32x4 m2a[2], v2a[2];
    #pragma unroll
    for (int rt = 0; rt < 2; ++rt) { m2a[rt] = (f32x4)0.f; v2a[rt] = (f32x4)0.f; }

    #pragma unroll
    for (int ks = 0; ks < 8; ++ks) {
        int f = w * 8 + ks;
        bf16x8 amu = *(const bf16x8*)(ws + WS_W2MU  + (size_t)(f * 64 + lane) * 8);
        bf16x8 ac  = *(const bf16x8*)(ws + WS_W2C   + (size_t)(f * 64 + lane) * 8);
        bf16x8 avr = *(const bf16x8*)(ws + WS_W2VAR + (size_t)(f * 64 + lane) * 8);
        #pragma unroll
        for (int rt = 0; rt < 2; ++rt) {
            int xrow = rt * 16 + lcol;
            int base = xrow * 256 + ((ks * 32 + lk * 8) ^ ((xrow & 7) << 3));
            bf16x8 bm  = *(const bf16x8*)&M1s[base];
            bf16x8 bv  = *(const bf16x8*)&V1s[base];
            bf16x8 bms = sq_bf16x8(bm);
            m2a[rt] = __builtin_amdgcn_mfma_f32_16x16x32_bf16(amu, bm,  m2a[rt], 0, 0, 0);
            v2a[rt] = __builtin_amdgcn_mfma_f32_16x16x32_bf16(ac,  bv,  v2a[rt], 0, 0, 0);
            v2a[rt] = __builtin_amdgcn_mfma_f32_16x16x32_bf16(avr, bms, v2a[rt], 0, 0, 0);
        }
    }

    __syncthreads();   // all layer-2 LDS reads done before slab reuse

    // ---------------- Transpose (p, p*m) through LDS ------------------------
    float* Pl = (float*)sh;            // [32][65]
    float* Ml = Pl + BM * 65;          // [32][65]
    #pragma unroll
    for (int rt = 0; rt < 2; ++rt) {
        int xrow = rt * 16 + lcol;
        int d1   = w * 16 + lk * 4;
        #pragma unroll
        for (int i = 0; i < 4; ++i) {
            float p = 1.0f / (v2a[rt][i] + EPSF);
            Pl[xrow * 65 + d1 + i] = p;
            Ml[xrow * 65 + d1 + i] = p * m2a[rt][i];
        }
    }

    __syncthreads();

    // ---------------- Emit: sorted slots OR row-coalesced atomics ----------
    #pragma unroll
    for (int r = 0; r < 8; ++r) {
        int row = w * 8 + r;
        int g   = Xidx[row0 + row];
        float pv = Pl[row * 65 + lane];
        float mv = Ml[row * 65 + lane];
        if constexpr (SORTED) {
            int pos;
            if (lane == 0) pos = offsets[g] + atomicAdd(&cursor[g], 1);
            pos = __shfl(pos, 0);
            float2 pm2; pm2.x = pv; pm2.y = mv;
            *(float2*)&vals[(size_t)pos * 128 + 2 * lane] = pm2;
        } else {
            atomicAdd(accP + (size_t)g * D1 + lane, pv);
            atomicAdd(accM + (size_t)g * D1 + lane, mv);
        }
    }
}

// --- per-segment reduce (sorted path): one wave per key ---------------------
__global__ void reduce_seg(const float* __restrict__ vals,
                           const int* __restrict__ offsets,
                           float* __restrict__ accM,
                           float* __restrict__ accP, int U)
{
    int key = blockIdx.x * 4 + (threadIdx.x >> 6);
    if (key >= U) return;
    int lane = threadIdx.x & 63;
    int s = offsets[key], e = offsets[key + 1];
    float psum = 0.f, msum = 0.f;
    for (int r = s; r < e; ++r) {
        float2 v = *(const float2*)&vals[(size_t)r * 128 + 2 * lane];
        psum += v.x; msum += v.y;
    }
    float var = 1.0f / (psum + EPSF);            // p_sum (+EPS) reciprocal
    accP[(size_t)key * D1 + lane] = var;         // embedd_vars
    accM[(size_t)key * D1 + lane] = msum * var;  // embedd_means
}

// --- finalize (fallback path only) ------------------------------------------
__global__ void dgp_finalize(float* __restrict__ accM,
                             float* __restrict__ accP, int total)
{
    int idx = blockIdx.x * blockDim.x + threadIdx.x;
    if (idx < total) {
        float var = 1.0f / (accP[idx] + EPSF);
        accP[idx] = var;
        accM[idx] = accM[idx] * var;
    }
}

extern "C" void kernel_launch(void* const* d_in, const int* in_sizes, int n_in,
                              void* d_out, int out_size, void* d_ws, size_t ws_size,
                              hipStream_t stream)
{
    const float* X     = (const float*)d_in[0];
    const int*   Xidx  = (const int*)d_in[1];
    const float* W1mu  = (const float*)d_in[2];
    const float* W1var = (const float*)d_in[3];
    const float* W2mu  = (const float*)d_in[4];
    const float* W2var = (const float*)d_in[5];

    const int N = in_sizes[0] / D0;            // 262144
    const int U = out_size / (2 * D1);         // 50000
    float* out  = (float*)d_out;
    float* accM = out;                          // means region
    float* accP = out + (size_t)U * D1;         // vars region
    ushort* ws  = (ushort*)d_ws;

    // sorted-path ws carve-out: counts[U+1] | cursor[U] | offsets[U+1] | vals
    char*  base    = (char*)d_ws;
    int*   counts  = (int*)(base + WS_WEIGHT_BYTES);
    int*   cursor  = counts + (U + 1);
    int*   offsets = cursor + U;
    size_t ctl_bytes_zero = (size_t)(2 * U + 1) * sizeof(int);   // counts+cursor
    size_t ctl_bytes_all  = (size_t)(3 * U + 2) * sizeof(int);
    size_t vals_off = (WS_WEIGHT_BYTES + ctl_bytes_all + 511) & ~(size_t)511;
    float* vals     = (float*)(base + vals_off);
    size_t needed   = vals_off + (size_t)N * 128 * sizeof(float);

    convert_w<<<56, 256, 0, stream>>>(W1mu, W1var, W2mu, W2var, ws);

    if (ws_size >= needed) {
        // counting-sort path: no fp atomics, exact segment sums
        hipMemsetAsync(counts, 0, ctl_bytes_zero, stream);
        hist_kernel<<<(N + 255) / 256, 256, 0, stream>>>(Xidx, counts, N);
        scan_kernel<<<1, 1024, 0, stream>>>(counts, offsets, U);
        dgp_mfma<true><<<N / BM, NT, 0, stream>>>(X, Xidx, ws, offsets, cursor,
                                                  vals, accM, accP);
        reduce_seg<<<(U + 3) / 4, 256, 0, stream>>>(vals, offsets, accM, accP, U);
    } else {
        // fallback: fp atomic scatter (round-5 behavior)
        hipMemsetAsync(d_out, 0, (size_t)out_size * sizeof(float), stream);
        dgp_mfma<false><<<N / BM, NT, 0, stream>>>(X, Xidx, ws, nullptr, nullptr,
                                                   nullptr, accM, accP);
        const int total = U * D1;
        dgp_finalize<<<(total + 255) / 256, 256, 0, stream>>>(accM, accP, total);
    }
}

// Round 7
// 255.653 us; speedup vs baseline: 1.3153x; 1.3153x over previous
//
#include <hip/hip_runtime.h>

#define EPSF 1e-8f

constexpr int D0 = 128;   // input dim
constexpr int R  = 256;   // random features
constexpr int D1 = 64;    // output dim
constexpr int BM = 32;    // rows per block
constexpr int NT = 256;   // threads per block (4 waves)

typedef __attribute__((ext_vector_type(8))) short  bf16x8;
typedef __attribute__((ext_vector_type(4))) float  f32x4;
typedef __attribute__((ext_vector_type(4))) uint   u32x4;

// ws layout (ushort elements): bf16 weights in MFMA fragment order
//   [0]      w1mu  frags (64 frags)
//   [32768]  w1var frags
//   [65536]  w2mu  frags (32 frags)          -> m2
//   [81920]  w2c   frags (= w2var + w2mu^2)  -> v2, multiplies v1
//   [98304]  w2var frags                     -> v2, multiplies m1^2
constexpr int WS_W1VAR = 32768;
constexpr int WS_W2MU  = 65536;
constexpr int WS_W2C   = 81920;
constexpr int WS_W2VAR = 98304;

__device__ __forceinline__ ushort f2bf(float x) {
    uint32_t u = __builtin_bit_cast(uint32_t, x);
    u += 0x7FFFu + ((u >> 16) & 1u);          // round-to-nearest-even
    return (ushort)(u >> 16);
}

// packed f32x2 -> bf16x2 (RNE), 1 VALU inst
__device__ __forceinline__ uint cvt_pk_bf16(float lo, float hi) {
    uint r;
    asm("v_cvt_pk_bf16_f32 %0, %1, %2" : "=v"(r) : "v"(lo), "v"(hi));
    return r;
}

// elementwise square of a bf16x8 fragment (bf16->f32 is a shift)
__device__ __forceinline__ bf16x8 sq_bf16x8(bf16x8 a) {
    u32x4 u = __builtin_bit_cast(u32x4, a);
    u32x4 r;
    #pragma unroll
    for (int i = 0; i < 4; ++i) {
        float lo = __builtin_bit_cast(float, u[i] << 16);
        float hi = __builtin_bit_cast(float, u[i] & 0xFFFF0000u);
        r[i] = cvt_pk_bf16(lo * lo, hi * hi);
    }
    return __builtin_bit_cast(bf16x8, r);
}

// --- pre-kernel: convert weights to bf16 in MFMA fragment order ------------
__global__ void convert_w(const float* __restrict__ W1mu,
                          const float* __restrict__ W1var,
                          const float* __restrict__ W2mu,
                          const float* __restrict__ W2var,
                          ushort* __restrict__ ws)
{
    int tid = blockIdx.x * 256 + threadIdx.x;
    if (tid < 8192) {                       // layer 1: 2 mats * 64 frags * 64 lanes
        int m    = tid >> 12;               // 0=mu 1=var
        int f    = (tid >> 6) & 63;         // frag = nt*4 + ks
        int lane = tid & 63;
        int nt = f >> 2, ks = f & 3;
        int col = nt * 16 + (lane & 15);    // rf index (W1 row)
        int k0  = ks * 32 + (lane >> 4) * 8;
        const float* src = (m ? W1var : W1mu) + (size_t)col * D0 + k0;
        ushort* dst = ws + (m ? WS_W1VAR : 0) + (size_t)(f * 64 + lane) * 8;
        #pragma unroll
        for (int j = 0; j < 8; ++j) dst[j] = f2bf(src[j]);
    } else if (tid < 8192 + 3 * 2048) {     // layer 2: 3 mats * 32 frags * 64 lanes
        int t2   = tid - 8192;
        int m    = t2 >> 11;                // 0=mu 1=c 2=var
        int f    = (t2 >> 6) & 31;          // frag = nt*8 + ks
        int lane = t2 & 63;
        int nt = f >> 3, ks = f & 7;
        int col = nt * 16 + (lane & 15);    // d1 index (W2 row)
        int k0  = ks * 32 + (lane >> 4) * 8;
        const float* smu = W2mu  + (size_t)col * R + k0;
        const float* svr = W2var + (size_t)col * R + k0;
        ushort* dst = ws + WS_W2MU + m * 16384 + (size_t)(f * 64 + lane) * 8;
        #pragma unroll
        for (int j = 0; j < 8; ++j) {
            float v;
            if (m == 0)      v = smu[j];
            else if (m == 1) v = fmaf(smu[j], smu[j], svr[j]);  // var + mu^2
            else             v = svr[j];
            dst[j] = f2bf(v);
        }
    }
}

// --- fused main kernel ------------------------------------------------------
// Operand-swapped GEMMs (D = W·X^T), 32 KB LDS -> 5 blocks/CU (160 KB exact).
// Layer-1 X loads software-pipelined one ks-step ahead; Xidx hoisted to entry.
__global__ __launch_bounds__(NT, 5)
void dgp_mfma(const float* __restrict__ X,
              const int*   __restrict__ Xidx,
              const ushort* __restrict__ ws,
              float* __restrict__ accM,
              float* __restrict__ accP)
{
    __shared__ __align__(16) ushort sh[2 * BM * R];
    ushort* M1s = sh;
    ushort* V1s = sh + BM * R;

    const int t    = threadIdx.x;
    const int lane = t & 63;
    const int w    = t >> 6;         // wave 0..3
    const int row0 = blockIdx.x * BM;
    const int lcol = lane & 15;      // X-row within 16-tile
    const int lk   = lane >> 4;      // 0..3

    // hoist segment ids: one load per lane at entry; used only after barriers
    const int gpre = Xidx[row0 + (lane & 31)];

    // ---------------- Layer 1: W1·X^T (mu) and W1var·(X^2)^T ----------------
    f32x4 accm[2][4], accv[2][4];   // [rt][nt]
    #pragma unroll
    for (int rt = 0; rt < 2; ++rt)
        #pragma unroll
        for (int nt = 0; nt < 4; ++nt) {
            accm[rt][nt] = (f32x4)0.f;
            accv[rt][nt] = (f32x4)0.f;
        }

    // prologue: issue ks=0 X loads
    float4 xcur[2][2];
    #pragma unroll
    for (int rt = 0; rt < 2; ++rt) {
        const float* xp = X + (size_t)(row0 + rt * 16 + lcol) * D0 + lk * 8;
        xcur[rt][0] = *(const float4*)xp;
        xcur[rt][1] = *(const float4*)(xp + 4);
    }

    #pragma unroll
    for (int ks = 0; ks < 4; ++ks) {
        // issue next-step X loads BEFORE consuming current (hide HBM latency)
        float4 xnxt[2][2];
        if (ks < 3) {
            #pragma unroll
            for (int rt = 0; rt < 2; ++rt) {
                const float* xp = X + (size_t)(row0 + rt * 16 + lcol) * D0
                                    + (ks + 1) * 32 + lk * 8;
                xnxt[rt][0] = *(const float4*)xp;
                xnxt[rt][1] = *(const float4*)(xp + 4);
            }
        }

        bf16x8 xb[2], xq[2];
        #pragma unroll
        for (int rt = 0; rt < 2; ++rt) {
            float4 a = xcur[rt][0];
            float4 b = xcur[rt][1];
            u32x4 um, uq;
            um[0] = cvt_pk_bf16(a.x, a.y);
            um[1] = cvt_pk_bf16(a.z, a.w);
            um[2] = cvt_pk_bf16(b.x, b.y);
            um[3] = cvt_pk_bf16(b.z, b.w);
            uq[0] = cvt_pk_bf16(a.x * a.x, a.y * a.y);
            uq[1] = cvt_pk_bf16(a.z * a.z, a.w * a.w);
            uq[2] = cvt_pk_bf16(b.x * b.x, b.y * b.y);
            uq[3] = cvt_pk_bf16(b.z * b.z, b.w * b.w);
            xb[rt] = __builtin_bit_cast(bf16x8, um);
            xq[rt] = __builtin_bit_cast(bf16x8, uq);
        }

        #pragma unroll
        for (int nt = 0; nt < 4; ++nt) {
            int f = (w * 4 + nt) * 4 + ks;
            bf16x8 amu = *(const bf16x8*)(ws + (size_t)(f * 64 + lane) * 8);
            bf16x8 avr = *(const bf16x8*)(ws + WS_W1VAR + (size_t)(f * 64 + lane) * 8);
            #pragma unroll
            for (int rt = 0; rt < 2; ++rt) {
                accm[rt][nt] = __builtin_amdgcn_mfma_f32_16x16x32_bf16(amu, xb[rt], accm[rt][nt], 0, 0, 0);
                accv[rt][nt] = __builtin_amdgcn_mfma_f32_16x16x32_bf16(avr, xq[rt], accv[rt][nt], 0, 0, 0);
            }
        }

        if (ks < 3) {
            #pragma unroll
            for (int rt = 0; rt < 2; ++rt) {
                xcur[rt][0] = xnxt[rt][0];
                xcur[rt][1] = xnxt[rt][1];
            }
        }
    }

    // RF-ReLU epilogue -> b64 LDS writes (XOR-swizzled)
    const float SCALE  = 0.08838834764831845f;  // sqrt(2/256)
    const float SCALE2 = 0.0078125f;            // 2/256
    #pragma unroll
    for (int rt = 0; rt < 2; ++rt) {
        int xrow = rt * 16 + lcol;
        int swz  = (xrow & 7) << 3;
        int rowb = xrow * 256;
        #pragma unroll
        for (int nt = 0; nt < 4; ++nt) {
            int rf0 = (w * 4 + nt) * 16 + lk * 4;
            float m1[4], v1[4];
            #pragma unroll
            for (int i = 0; i < 4; ++i) {
                float om = accm[rt][nt][i];
                float ov = accv[rt][nt][i];
                bool pos = om > 0.f;
                m1[i] = pos ? SCALE  * om : 0.f;
                v1[i] = pos ? SCALE2 * ov : 0.f;
            }
            uint2 pm, pv;
            pm.x = cvt_pk_bf16(m1[0], m1[1]); pm.y = cvt_pk_bf16(m1[2], m1[3]);
            pv.x = cvt_pk_bf16(v1[0], v1[1]); pv.y = cvt_pk_bf16(v1[2], v1[3]);
            int idx = rowb + (rf0 ^ swz);
            *(uint2*)&M1s[idx] = pm;
            *(uint2*)&V1s[idx] = pv;
        }
    }

    __syncthreads();

    // ---------------- Layer 2: W2·slab^T moment GEMMs (K=256) ---------------
    f32x4 m2a[2], v2a[2];
    #pragma unroll
    for (int rt = 0; rt < 2; ++rt) { m2a[rt] = (f32x4)0.f; v2a[rt] = (f32x4)0.f; }

    #pragma unroll
    for (int ks = 0; ks < 8; ++ks) {
        int f = w * 8 + ks;
        bf16x8 amu = *(const bf16x8*)(ws + WS_W2MU  + (size_t)(f * 64 + lane) * 8);
        bf16x8 ac  = *(const bf16x8*)(ws + WS_W2C   + (size_t)(f * 64 + lane) * 8);
        bf16x8 avr = *(const bf16x8*)(ws + WS_W2VAR + (size_t)(f * 64 + lane) * 8);
        #pragma unroll
        for (int rt = 0; rt < 2; ++rt) {
            int xrow = rt * 16 + lcol;
            int base = xrow * 256 + ((ks * 32 + lk * 8) ^ ((xrow & 7) << 3));
            bf16x8 bm  = *(const bf16x8*)&M1s[base];
            bf16x8 bv  = *(const bf16x8*)&V1s[base];
            bf16x8 bms = sq_bf16x8(bm);
            m2a[rt] = __builtin_amdgcn_mfma_f32_16x16x32_bf16(amu, bm,  m2a[rt], 0, 0, 0);
            v2a[rt] = __builtin_amdgcn_mfma_f32_16x16x32_bf16(ac,  bv,  v2a[rt], 0, 0, 0);
            v2a[rt] = __builtin_amdgcn_mfma_f32_16x16x32_bf16(avr, bms, v2a[rt], 0, 0, 0);
        }
    }

    __syncthreads();   // all layer-2 LDS reads done before slab reuse

    // ---------------- Transpose (p, p*m) through LDS ------------------------
    float* Pl = (float*)sh;            // [32][65]
    float* Ml = Pl + BM * 65;          // [32][65]
    #pragma unroll
    for (int rt = 0; rt < 2; ++rt) {
        int xrow = rt * 16 + lcol;
        int d1   = w * 16 + lk * 4;
        #pragma unroll
        for (int i = 0; i < 4; ++i) {
            float p = 1.0f / (v2a[rt][i] + EPSF);
            Pl[xrow * 65 + d1 + i] = p;
            Ml[xrow * 65 + d1 + i] = p * m2a[rt][i];
        }
    }

    __syncthreads();

    // ---------------- Row-coalesced atomic scatter --------------------------
    // wave w handles rows w*8 .. w*8+7; per instruction: one uniform row,
    // 64 lanes = 64 consecutive floats = 256B dense region
    #pragma unroll
    for (int r = 0; r < 8; ++r) {
        int row = w * 8 + r;
        int g   = __builtin_amdgcn_readfirstlane(__shfl(gpre, row));
        float pv = Pl[row * 65 + lane];
        float mv = Ml[row * 65 + lane];
        atomicAdd(accP + (size_t)g * D1 + lane, pv);
        atomicAdd(accM + (size_t)g * D1 + lane, mv);
    }
}

__global__ void dgp_finalize(float* __restrict__ accM,
                             float* __restrict__ accP, int total)
{
    int idx = blockIdx.x * blockDim.x + threadIdx.x;
    if (idx < total) {
        float var = 1.0f / (accP[idx] + EPSF);   // p_sum = seg_sum + EPS
        accP[idx] = var;                         // embedd_vars
        accM[idx] = accM[idx] * var;             // embedd_means
    }
}

extern "C" void kernel_launch(void* const* d_in, const int* in_sizes, int n_in,
                              void* d_out, int out_size, void* d_ws, size_t ws_size,
                              hipStream_t stream)
{
    const float* X     = (const float*)d_in[0];
    const int*   Xidx  = (const int*)d_in[1];
    const float* W1mu  = (const float*)d_in[2];
    const float* W1var = (const float*)d_in[3];
    const float* W2mu  = (const float*)d_in[4];
    const float* W2var = (const float*)d_in[5];

    const int N = in_sizes[0] / D0;            // 262144
    const int U = out_size / (2 * D1);         // 50000
    float* out  = (float*)d_out;
    float* accM = out;                          // means region
    float* accP = out + (size_t)U * D1;         // vars region
    ushort* ws  = (ushort*)d_ws;

    // harness does not re-poison between replays: re-zero accumulators
    hipMemsetAsync(d_out, 0, (size_t)out_size * sizeof(float), stream);

    convert_w<<<56, 256, 0, stream>>>(W1mu, W1var, W2mu, W2var, ws);

    dgp_mfma<<<N / BM, NT, 0, stream>>>(X, Xidx, ws, accM, accP);

    const int total = U * D1;
    dgp_finalize<<<(total + 255) / 256, 256, 0, stream>>>(accM, accP, total);
}

// Round 8
// 194.100 us; speedup vs baseline: 1.7324x; 1.3171x over previous
//
#include <hip/hip_runtime.h>

#define EPSF 1e-8f

constexpr int D0 = 128;   // input dim
constexpr int R  = 256;   // random features
constexpr int D1 = 64;    // output dim
constexpr int BM = 32;    // rows per block
constexpr int NT = 256;   // threads per block (4 waves)

typedef __attribute__((ext_vector_type(8))) short  bf16x8;
typedef __attribute__((ext_vector_type(4))) float  f32x4;
typedef __attribute__((ext_vector_type(4))) uint   u32x4;

// ws layout (ushort elements): bf16 weights in MFMA fragment order
//   [0]      w1mu  frags (64 frags)
//   [32768]  w1var frags
//   [65536]  w2mu  frags (32 frags)          -> m2
//   [81920]  w2c   frags (= w2var + w2mu^2)  -> v2, multiplies v1
//   [98304]  w2var frags                     -> v2, multiplies m1^2
constexpr int WS_W1VAR = 32768;
constexpr int WS_W2MU  = 65536;
constexpr int WS_W2C   = 81920;
constexpr int WS_W2VAR = 98304;

__device__ __forceinline__ ushort f2bf(float x) {
    uint32_t u = __builtin_bit_cast(uint32_t, x);
    u += 0x7FFFu + ((u >> 16) & 1u);          // round-to-nearest-even
    return (ushort)(u >> 16);
}

// packed f32x2 -> bf16x2 (RNE), 1 VALU inst
__device__ __forceinline__ uint cvt_pk_bf16(float lo, float hi) {
    uint r;
    asm("v_cvt_pk_bf16_f32 %0, %1, %2" : "=v"(r) : "v"(lo), "v"(hi));
    return r;
}

// elementwise square of a bf16x8 fragment (bf16->f32 is a shift)
__device__ __forceinline__ bf16x8 sq_bf16x8(bf16x8 a) {
    u32x4 u = __builtin_bit_cast(u32x4, a);
    u32x4 r;
    #pragma unroll
    for (int i = 0; i < 4; ++i) {
        float lo = __builtin_bit_cast(float, u[i] << 16);
        float hi = __builtin_bit_cast(float, u[i] & 0xFFFF0000u);
        r[i] = cvt_pk_bf16(lo * lo, hi * hi);
    }
    return __builtin_bit_cast(bf16x8, r);
}

// --- pre-kernel: convert weights to bf16 in MFMA fragment order ------------
__global__ void convert_w(const float* __restrict__ W1mu,
                          const float* __restrict__ W1var,
                          const float* __restrict__ W2mu,
                          const float* __restrict__ W2var,
                          ushort* __restrict__ ws)
{
    int tid = blockIdx.x * 256 + threadIdx.x;
    if (tid < 8192) {                       // layer 1: 2 mats * 64 frags * 64 lanes
        int m    = tid >> 12;               // 0=mu 1=var
        int f    = (tid >> 6) & 63;         // frag = nt*4 + ks
        int lane = tid & 63;
        int nt = f >> 2, ks = f & 3;
        int col = nt * 16 + (lane & 15);    // rf index (W1 row)
        int k0  = ks * 32 + (lane >> 4) * 8;
        const float* src = (m ? W1var : W1mu) + (size_t)col * D0 + k0;
        ushort* dst = ws + (m ? WS_W1VAR : 0) + (size_t)(f * 64 + lane) * 8;
        #pragma unroll
        for (int j = 0; j < 8; ++j) dst[j] = f2bf(src[j]);
    } else if (tid < 8192 + 3 * 2048) {     // layer 2: 3 mats * 32 frags * 64 lanes
        int t2   = tid - 8192;
        int m    = t2 >> 11;                // 0=mu 1=c 2=var
        int f    = (t2 >> 6) & 31;          // frag = nt*8 + ks
        int lane = t2 & 63;
        int nt = f >> 3, ks = f & 7;
        int col = nt * 16 + (lane & 15);    // d1 index (W2 row)
        int k0  = ks * 32 + (lane >> 4) * 8;
        const float* smu = W2mu  + (size_t)col * R + k0;
        const float* svr = W2var + (size_t)col * R + k0;
        ushort* dst = ws + WS_W2MU + m * 16384 + (size_t)(f * 64 + lane) * 8;
        #pragma unroll
        for (int j = 0; j < 8; ++j) {
            float v;
            if (m == 0)      v = smu[j];
            else if (m == 1) v = fmaf(smu[j], smu[j], svr[j]);  // var + mu^2
            else             v = svr[j];
            dst[j] = f2bf(v);
        }
    }
}

// --- fused main kernel ------------------------------------------------------
// Operand-swapped GEMMs (D = W·X^T). 32 KB LDS, __launch_bounds__(256,4)
// (VGPR cap 128 — r7 showed bound-5 caps at 48 and spills).
// Pipelining: X 1-ks ahead; W2 frags double-buffered with prologue issued
// BEFORE the barrier; layer-2 LDS reads 1 step ahead.
__global__ __launch_bounds__(NT, 4)
void dgp_mfma(const float* __restrict__ X,
              const int*   __restrict__ Xidx,
              const ushort* __restrict__ ws,
              float* __restrict__ accM,
              float* __restrict__ accP)
{
    __shared__ __align__(16) ushort sh[2 * BM * R];
    ushort* M1s = sh;
    ushort* V1s = sh + BM * R;

    const int t    = threadIdx.x;
    const int lane = t & 63;
    const int w    = t >> 6;         // wave 0..3
    const int row0 = blockIdx.x * BM;
    const int lcol = lane & 15;      // X-row within 16-tile
    const int lk   = lane >> 4;      // 0..3

    // ---------------- Layer 1: W1·X^T (mu) and W1var·(X^2)^T ----------------
    f32x4 accm[2][4], accv[2][4];   // [rt][nt]
    #pragma unroll
    for (int rt = 0; rt < 2; ++rt)
        #pragma unroll
        for (int nt = 0; nt < 4; ++nt) {
            accm[rt][nt] = (f32x4)0.f;
            accv[rt][nt] = (f32x4)0.f;
        }

    // prologue: issue ks=0 X loads
    float4 xcur[2][2];
    #pragma unroll
    for (int rt = 0; rt < 2; ++rt) {
        const float* xp = X + (size_t)(row0 + rt * 16 + lcol) * D0 + lk * 8;
        xcur[rt][0] = *(const float4*)xp;
        xcur[rt][1] = *(const float4*)(xp + 4);
    }

    #pragma unroll
    for (int ks = 0; ks < 4; ++ks) {
        // issue next-step X loads BEFORE consuming current (hide L3 latency)
        float4 xnxt[2][2];
        if (ks < 3) {
            #pragma unroll
            for (int rt = 0; rt < 2; ++rt) {
                const float* xp = X + (size_t)(row0 + rt * 16 + lcol) * D0
                                    + (ks + 1) * 32 + lk * 8;
                xnxt[rt][0] = *(const float4*)xp;
                xnxt[rt][1] = *(const float4*)(xp + 4);
            }
        }

        bf16x8 xb[2], xq[2];
        #pragma unroll
        for (int rt = 0; rt < 2; ++rt) {
            float4 a = xcur[rt][0];
            float4 b = xcur[rt][1];
            u32x4 um, uq;
            um[0] = cvt_pk_bf16(a.x, a.y);
            um[1] = cvt_pk_bf16(a.z, a.w);
            um[2] = cvt_pk_bf16(b.x, b.y);
            um[3] = cvt_pk_bf16(b.z, b.w);
            uq[0] = cvt_pk_bf16(a.x * a.x, a.y * a.y);
            uq[1] = cvt_pk_bf16(a.z * a.z, a.w * a.w);
            uq[2] = cvt_pk_bf16(b.x * b.x, b.y * b.y);
            uq[3] = cvt_pk_bf16(b.z * b.z, b.w * b.w);
            xb[rt] = __builtin_bit_cast(bf16x8, um);
            xq[rt] = __builtin_bit_cast(bf16x8, uq);
        }

        #pragma unroll
        for (int nt = 0; nt < 4; ++nt) {
            int f = (w * 4 + nt) * 4 + ks;
            bf16x8 amu = *(const bf16x8*)(ws + (size_t)(f * 64 + lane) * 8);
            bf16x8 avr = *(const bf16x8*)(ws + WS_W1VAR + (size_t)(f * 64 + lane) * 8);
            #pragma unroll
            for (int rt = 0; rt < 2; ++rt) {
                accm[rt][nt] = __builtin_amdgcn_mfma_f32_16x16x32_bf16(amu, xb[rt], accm[rt][nt], 0, 0, 0);
                accv[rt][nt] = __builtin_amdgcn_mfma_f32_16x16x32_bf16(avr, xq[rt], accv[rt][nt], 0, 0, 0);
            }
        }

        if (ks < 3) {
            #pragma unroll
            for (int rt = 0; rt < 2; ++rt) {
                xcur[rt][0] = xnxt[rt][0];
                xcur[rt][1] = xnxt[rt][1];
            }
        }
    }

    // RF-ReLU epilogue -> b64 LDS writes (XOR-swizzled)
    const float SCALE  = 0.08838834764831845f;  // sqrt(2/256)
    const float SCALE2 = 0.0078125f;            // 2/256
    #pragma unroll
    for (int rt = 0; rt < 2; ++rt) {
        int xrow = rt * 16 + lcol;
        int swz  = (xrow & 7) << 3;
        int rowb = xrow * 256;
        #pragma unroll
        for (int nt = 0; nt < 4; ++nt) {
            int rf0 = (w * 4 + nt) * 16 + lk * 4;
            float m1[4], v1[4];
            #pragma unroll
            for (int i = 0; i < 4; ++i) {
                float om = accm[rt][nt][i];
                float ov = accv[rt][nt][i];
                bool pos = om > 0.f;
                m1[i] = pos ? SCALE  * om : 0.f;
                v1[i] = pos ? SCALE2 * ov : 0.f;
            }
            uint2 pm, pv;
            pm.x = cvt_pk_bf16(m1[0], m1[1]); pm.y = cvt_pk_bf16(m1[2], m1[3]);
            pv.x = cvt_pk_bf16(v1[0], v1[1]); pv.y = cvt_pk_bf16(v1[2], v1[3]);
            int idx = rowb + (rf0 ^ swz);
            *(uint2*)&M1s[idx] = pm;
            *(uint2*)&V1s[idx] = pv;
        }
    }

    // prologue: issue first W2 frags BEFORE the barrier (L2 latency hides
    // under the barrier wait; these loads don't depend on LDS)
    bf16x8 pamu, pac, pavr;
    {
        int f = w * 8;
        pamu = *(const bf16x8*)(ws + WS_W2MU  + (size_t)(f * 64 + lane) * 8);
        pac  = *(const bf16x8*)(ws + WS_W2C   + (size_t)(f * 64 + lane) * 8);
        pavr = *(const bf16x8*)(ws + WS_W2VAR + (size_t)(f * 64 + lane) * 8);
    }

    __syncthreads();

    // ---------------- Layer 2: W2·slab^T moment GEMMs (K=256) ---------------
    f32x4 m2a[2], v2a[2];
    #pragma unroll
    for (int rt = 0; rt < 2; ++rt) { m2a[rt] = (f32x4)0.f; v2a[rt] = (f32x4)0.f; }

    // LDS prefetch for ks=0
    bf16x8 pbm[2], pbv[2];
    #pragma unroll
    for (int rt = 0; rt < 2; ++rt) {
        int xrow = rt * 16 + lcol;
        int base = xrow * 256 + ((lk * 8) ^ ((xrow & 7) << 3));
        pbm[rt] = *(const bf16x8*)&M1s[base];
        pbv[rt] = *(const bf16x8*)&V1s[base];
    }

    #pragma unroll
    for (int ks = 0; ks < 8; ++ks) {
        bf16x8 namu, nac, navr, nbm[2], nbv[2];
        if (ks < 7) {
            int f = w * 8 + ks + 1;
            namu = *(const bf16x8*)(ws + WS_W2MU  + (size_t)(f * 64 + lane) * 8);
            nac  = *(const bf16x8*)(ws + WS_W2C   + (size_t)(f * 64 + lane) * 8);
            navr = *(const bf16x8*)(ws + WS_W2VAR + (size_t)(f * 64 + lane) * 8);
            #pragma unroll
            for (int rt = 0; rt < 2; ++rt) {
                int xrow = rt * 16 + lcol;
                int base = xrow * 256 + (((ks + 1) * 32 + lk * 8) ^ ((xrow & 7) << 3));
                nbm[rt] = *(const bf16x8*)&M1s[base];
                nbv[rt] = *(const bf16x8*)&V1s[base];
            }
        }
        #pragma unroll
        for (int rt = 0; rt < 2; ++rt) {
            bf16x8 bms = sq_bf16x8(pbm[rt]);
            m2a[rt] = __builtin_amdgcn_mfma_f32_16x16x32_bf16(pamu, pbm[rt], m2a[rt], 0, 0, 0);
            v2a[rt] = __builtin_amdgcn_mfma_f32_16x16x32_bf16(pac,  pbv[rt], v2a[rt], 0, 0, 0);
            v2a[rt] = __builtin_amdgcn_mfma_f32_16x16x32_bf16(pavr, bms,     v2a[rt], 0, 0, 0);
        }
        if (ks < 7) {
            pamu = namu; pac = nac; pavr = navr;
            #pragma unroll
            for (int rt = 0; rt < 2; ++rt) { pbm[rt] = nbm[rt]; pbv[rt] = nbv[rt]; }
        }
    }

    __syncthreads();   // all layer-2 LDS reads done before slab reuse

    // ---------------- Transpose (p, p*m) through LDS ------------------------
    float* Pl = (float*)sh;            // [32][65]
    float* Ml = Pl + BM * 65;          // [32][65]
    #pragma unroll
    for (int rt = 0; rt < 2; ++rt) {
        int xrow = rt * 16 + lcol;
        int d1   = w * 16 + lk * 4;
        #pragma unroll
        for (int i = 0; i < 4; ++i) {
            float p = 1.0f / (v2a[rt][i] + EPSF);
            Pl[xrow * 65 + d1 + i] = p;
            Ml[xrow * 65 + d1 + i] = p * m2a[rt][i];
        }
    }

    __syncthreads();

    // ---------------- Row-coalesced atomic scatter --------------------------
    // wave w handles rows w*8 .. w*8+7; per instruction: one uniform row,
    // 64 lanes = 64 consecutive floats = 256B dense region
    #pragma unroll
    for (int r = 0; r < 8; ++r) {
        int row = w * 8 + r;
        int g   = __builtin_amdgcn_readfirstlane(Xidx[row0 + row]);
        float pv = Pl[row * 65 + lane];
        float mv = Ml[row * 65 + lane];
        atomicAdd(accP + (size_t)g * D1 + lane, pv);
        atomicAdd(accM + (size_t)g * D1 + lane, mv);
    }
}

__global__ void dgp_finalize(float* __restrict__ accM,
                             float* __restrict__ accP, int total)
{
    int idx = blockIdx.x * blockDim.x + threadIdx.x;
    if (idx < total) {
        float var = 1.0f / (accP[idx] + EPSF);   // p_sum = seg_sum + EPS
        accP[idx] = var;                         // embedd_vars
        accM[idx] = accM[idx] * var;             // embedd_means
    }
}

extern "C" void kernel_launch(void* const* d_in, const int* in_sizes, int n_in,
                              void* d_out, int out_size, void* d_ws, size_t ws_size,
                              hipStream_t stream)
{
    const float* X     = (const float*)d_in[0];
    const int*   Xidx  = (const int*)d_in[1];
    const float* W1mu  = (const float*)d_in[2];
    const float* W1var = (const float*)d_in[3];
    const float* W2mu  = (const float*)d_in[4];
    const float* W2var = (const float*)d_in[5];

    const int N = in_sizes[0] / D0;            // 262144
    const int U = out_size / (2 * D1);         // 50000
    float* out  = (float*)d_out;
    float* accM = out;                          // means region
    float* accP = out + (size_t)U * D1;         // vars region
    ushort* ws  = (ushort*)d_ws;

    // harness does not re-poison between replays: re-zero accumulators
    hipMemsetAsync(d_out, 0, (size_t)out_size * sizeof(float), stream);

    convert_w<<<56, 256, 0, stream>>>(W1mu, W1var, W2mu, W2var, ws);

    dgp_mfma<<<N / BM, NT, 0, stream>>>(X, Xidx, ws, accM, accP);

    const int total = U * D1;
    dgp_finalize<<<(total + 255) / 256, 256, 0, stream>>>(accM, accP, total);
}